// Round 1
// baseline (650.977 us; speedup 1.0000x reference)
//
#include <hip/hip_runtime.h>
#include <math.h>

constexpr int FRAMES = 32;
constexpr int HW = 720 * 1280;              // 921600 pixels per frame
constexpr long long NTOT = (long long)FRAMES * HW;
constexpr int NB = 1 << 20;                 // rank histogram buckets
constexpr int CHUNK = 1024;
constexpr int NCHUNK = NB / CHUNK;          // 1024
constexpr int BPF = 32;                     // blocks per frame for big passes
constexpr size_t HIST_BYTES = (size_t)NB * sizeof(unsigned);

struct Accum {
  double sumP[FRAMES], sumP2[FRAMES], sumFixP[FRAMES], sumG[FRAMES], simSum[FRAMES];
  unsigned cntFix[FRAMES];
  unsigned long long S_cg;      // sum of count_greater over fixation pixels (frame 0)
  unsigned maxCG, Nf0;
  float minP, maxP, minG, maxG, min0, max0, inv0;
  double d_minP, d_scaleP, d_minG, d_scaleG;
  unsigned chunkTotal[NCHUNK];  // becomes exclusive chunk suffix after k_scan
};

// ---------- wave(64) reduction helpers ----------
__device__ inline double wredd(double v) {
  for (int o = 32; o; o >>= 1) v += __shfl_down(v, o, 64);
  return v;
}
__device__ inline unsigned wredu(unsigned v) {
  for (int o = 32; o; o >>= 1) v += __shfl_down(v, o, 64);
  return v;
}
__device__ inline unsigned long long wredull(unsigned long long v) {
  for (int o = 32; o; o >>= 1) v += __shfl_down(v, o, 64);
  return v;
}
__device__ inline unsigned wredumax(unsigned v) {
  for (int o = 32; o; o >>= 1) { unsigned t = __shfl_down(v, o, 64); v = v > t ? v : t; }
  return v;
}
__device__ inline float wredfmin(float v) {
  for (int o = 32; o; o >>= 1) v = fminf(v, __shfl_down(v, o, 64));
  return v;
}
__device__ inline float wredfmax(float v) {
  for (int o = 32; o; o >>= 1) v = fmaxf(v, __shfl_down(v, o, 64));
  return v;
}

__device__ inline void atomicMinF(float* addr, float val) {
  unsigned* a = (unsigned*)addr;
  unsigned old = *a;
  while (val < __uint_as_float(old)) {
    unsigned prev = atomicCAS(a, old, __float_as_uint(val));
    if (prev == old) break;
    old = prev;
  }
}
__device__ inline void atomicMaxF(float* addr, float val) {
  unsigned* a = (unsigned*)addr;
  unsigned old = *a;
  while (val > __uint_as_float(old)) {
    unsigned prev = atomicCAS(a, old, __float_as_uint(val));
    if (prev == old) break;
    old = prev;
  }
}

__device__ inline int bucket_of(float x, float mn, float inv) {
  int b = (int)((x - mn) * inv);
  b = b < 0 ? 0 : b;
  return b > NB - 1 ? NB - 1 : b;
}

// ---------- kernels ----------
__global__ void k_init(Accum* acc) {
  acc->minP = __builtin_inff();  acc->maxP = -__builtin_inff();
  acc->minG = __builtin_inff();  acc->maxG = -__builtin_inff();
  acc->min0 = __builtin_inff();  acc->max0 = -__builtin_inff();
}

// Pass 1: global min/max + global sums + per-frame {sumP, sumP2, sumFixP, cntFix}
__global__ void k_pass1(const float* __restrict__ pred, const float* __restrict__ gt,
                        const int* __restrict__ fix, Accum* __restrict__ acc) {
  const int f = blockIdx.x / BPF;
  const int bi = blockIdx.x % BPF;
  const float4* p4 = (const float4*)(pred + (size_t)f * HW);
  const float4* g4 = (const float4*)(gt + (size_t)f * HW);
  const int4* m4 = (const int4*)(fix + (size_t)f * HW);
  const int n4 = HW / 4;
  double sP = 0, sP2 = 0, sG = 0, sFP = 0;
  unsigned cnt = 0;
  float mnP = __builtin_inff(), mxP = -__builtin_inff();
  float mnG = __builtin_inff(), mxG = -__builtin_inff();
  for (int i = bi * 256 + threadIdx.x; i < n4; i += BPF * 256) {
    float4 p = p4[i]; float4 g = g4[i]; int4 m = m4[i];
    float pe[4] = {p.x, p.y, p.z, p.w};
    float ge[4] = {g.x, g.y, g.z, g.w};
    int me[4] = {m.x, m.y, m.z, m.w};
#pragma unroll
    for (int j = 0; j < 4; ++j) {
      double pd = (double)pe[j];
      sP += pd; sP2 += pd * pd; sG += (double)ge[j];
      if (me[j] != 0) { sFP += pd; cnt++; }
      mnP = fminf(mnP, pe[j]); mxP = fmaxf(mxP, pe[j]);
      mnG = fminf(mnG, ge[j]); mxG = fmaxf(mxG, ge[j]);
    }
  }
  sP = wredd(sP); sP2 = wredd(sP2); sG = wredd(sG); sFP = wredd(sFP);
  cnt = wredu(cnt);
  mnP = wredfmin(mnP); mxP = wredfmax(mxP);
  mnG = wredfmin(mnG); mxG = wredfmax(mxG);
  if ((threadIdx.x & 63) == 0) {
    atomicAdd(&acc->sumP[f], sP);
    atomicAdd(&acc->sumP2[f], sP2);
    atomicAdd(&acc->sumG[f], sG);
    atomicAdd(&acc->sumFixP[f], sFP);
    atomicAdd(&acc->cntFix[f], cnt);
    atomicMinF(&acc->minP, mnP); atomicMaxF(&acc->maxP, mxP);
    atomicMinF(&acc->minG, mnG); atomicMaxF(&acc->maxG, mxG);
    if (f == 0) { atomicMinF(&acc->min0, mnP); atomicMaxF(&acc->max0, mxP); }
  }
}

__global__ void k_derive(Accum* acc) {
  double sp = 0, sg = 0;
  for (int f = 0; f < FRAMES; ++f) { sp += acc->sumP[f]; sg += acc->sumG[f]; }
  acc->d_minP = (double)acc->minP;
  acc->d_minG = (double)acc->minG;
  acc->d_scaleP = 1.0 / (sp - (double)NTOT * acc->d_minP);
  acc->d_scaleG = 1.0 / (sg - (double)NTOT * acc->d_minG);
  acc->inv0 = (float)NB / (acc->max0 - acc->min0);
}

// Histogram of pred[0] into NB buckets (monotone in value -> rank-exact up to in-bucket ties)
__global__ void k_hist(const float* __restrict__ pred, unsigned* __restrict__ hist,
                       const Accum* __restrict__ acc) {
  const float mn = acc->min0, inv = acc->inv0;
  for (int i = blockIdx.x * blockDim.x + threadIdx.x; i < HW; i += gridDim.x * blockDim.x)
    atomicAdd(&hist[bucket_of(pred[i], mn, inv)], 1u);
}

// Per-chunk totals
__global__ void k_chunktot(const unsigned* __restrict__ hist, Accum* __restrict__ acc) {
  __shared__ unsigned sw[4];
  const int c = blockIdx.x;
  unsigned s = 0;
  for (int t = threadIdx.x; t < CHUNK; t += blockDim.x) s += hist[(size_t)c * CHUNK + t];
  s = wredu(s);
  if ((threadIdx.x & 63) == 0) sw[threadIdx.x >> 6] = s;
  __syncthreads();
  if (threadIdx.x == 0) acc->chunkTotal[c] = sw[0] + sw[1] + sw[2] + sw[3];
}

// Single-block exclusive suffix scan over NCHUNK chunk totals (in place)
__global__ void k_scan(Accum* acc) {
  __shared__ unsigned s[NCHUNK];
  const int t = threadIdx.x;
  unsigned v = acc->chunkTotal[t];
  s[t] = v;
  __syncthreads();
  for (int off = 1; off < NCHUNK; off <<= 1) {
    unsigned a = (t + off < NCHUNK) ? s[t + off] : 0u;
    __syncthreads();
    s[t] += a;
    __syncthreads();
  }
  acc->chunkTotal[t] = s[t] - v;  // strictly-greater-chunk sum
}

// In place: hist[b] := #elements in buckets strictly greater than b
__global__ void k_apply(unsigned* __restrict__ hist, const Accum* __restrict__ acc) {
  __shared__ unsigned s[CHUNK];
  const int c = blockIdx.x, t = threadIdx.x;
  unsigned v = hist[(size_t)c * CHUNK + t];
  s[t] = v;
  __syncthreads();
  for (int off = 1; off < CHUNK; off <<= 1) {
    unsigned a = (t + off < CHUNK) ? s[t + off] : 0u;
    __syncthreads();
    s[t] += a;
    __syncthreads();
  }
  hist[(size_t)c * CHUNK + t] = acc->chunkTotal[c] + (s[t] - v);
}

// Accumulate sum / max of count_greater over fixation pixels of frame 0
__global__ void k_fixpass(const float* __restrict__ pred, const int* __restrict__ fix,
                          const unsigned* __restrict__ hist, Accum* __restrict__ acc) {
  const float mn = acc->min0, inv = acc->inv0;
  unsigned long long s = 0;
  unsigned mx = 0, c = 0;
  for (int i = blockIdx.x * blockDim.x + threadIdx.x; i < HW; i += gridDim.x * blockDim.x) {
    if (fix[i] > 0) {
      unsigned cg = hist[bucket_of(pred[i], mn, inv)];
      s += cg;
      mx = cg > mx ? cg : mx;
      c++;
    }
  }
  s = wredull(s); mx = wredumax(mx); c = wredu(c);
  if ((threadIdx.x & 63) == 0) {
    atomicAdd(&acc->S_cg, s);
    atomicMax(&acc->maxCG, mx);
    atomicAdd(&acc->Nf0, c);
  }
}

// Pass 2: SIM per-frame sum of min(p_norm, g_norm) where g > g_min
__global__ void k_pass2(const float* __restrict__ pred, const float* __restrict__ gt,
                        Accum* __restrict__ acc) {
  const int f = blockIdx.x / BPF;
  const int bi = blockIdx.x % BPF;
  const float4* p4 = (const float4*)(pred + (size_t)f * HW);
  const float4* g4 = (const float4*)(gt + (size_t)f * HW);
  const int n4 = HW / 4;
  const double minP = acc->d_minP, sclP = acc->d_scaleP;
  const double minG = acc->d_minG, sclG = acc->d_scaleG;
  const float fminG = acc->minG;
  double s = 0;
  for (int i = bi * 256 + threadIdx.x; i < n4; i += BPF * 256) {
    float4 p = p4[i]; float4 g = g4[i];
    float pe[4] = {p.x, p.y, p.z, p.w};
    float ge[4] = {g.x, g.y, g.z, g.w};
#pragma unroll
    for (int j = 0; j < 4; ++j) {
      if (ge[j] > fminG) {
        double pn = ((double)pe[j] - minP) * sclP;
        double gn = ((double)ge[j] - minG) * sclG;
        s += pn < gn ? pn : gn;
      }
    }
  }
  s = wredd(s);
  if ((threadIdx.x & 63) == 0) atomicAdd(&acc->simSum[f], s);
}

__global__ void k_final(const Accum* __restrict__ acc, float* __restrict__ out) {
  if (threadIdx.x != 0 || blockIdx.x != 0) return;
  double sim = 0, nss = 0;
  for (int f = 0; f < FRAMES; ++f) sim += acc->simSum[f];
  sim /= FRAMES;
  for (int f = 0; f < FRAMES; ++f) {
    double mean = acc->sumP[f] / (double)HW;
    double var = acc->sumP2[f] / (double)HW - mean * mean;
    double sd = sqrt(var);
    double cnt = (double)acc->cntFix[f];
    nss += (acc->sumFixP[f] - cnt * mean) / sd / cnt;
  }
  nss /= FRAMES;
  // AUC-Judd closed form: AUC = [2NfD + (Nf-1)^2 + R_last - 2*SumR] / (2NfD)
  double Nf = (double)acc->Nf0;
  double D = (double)HW - Nf;
  double SumR = (double)acc->S_cg + Nf;         // ranks are count_greater + 1
  double Rlast = (double)acc->maxCG + 1.0;
  double auc = (2.0 * Nf * D + (Nf - 1.0) * (Nf - 1.0) + Rlast - 2.0 * SumR) / (2.0 * Nf * D);
  out[0] = (float)(auc + sim + nss);
  out[1] = (float)auc;
  out[2] = (float)sim;
  out[3] = (float)nss;
}

extern "C" void kernel_launch(void* const* d_in, const int* in_sizes, int n_in,
                              void* d_out, int out_size, void* d_ws, size_t ws_size,
                              hipStream_t stream) {
  const float* pred = (const float*)d_in[0];
  const float* gt = (const float*)d_in[1];
  const int* fix = (const int*)d_in[2];
  float* out = (float*)d_out;
  unsigned* hist = (unsigned*)d_ws;
  Accum* acc = (Accum*)((char*)d_ws + HIST_BYTES);

  hipMemsetAsync(d_ws, 0, HIST_BYTES + sizeof(Accum), stream);
  k_init<<<1, 1, 0, stream>>>(acc);
  k_pass1<<<FRAMES * BPF, 256, 0, stream>>>(pred, gt, fix, acc);
  k_derive<<<1, 1, 0, stream>>>(acc);
  k_hist<<<1024, 256, 0, stream>>>(pred, hist, acc);
  k_chunktot<<<NCHUNK, 256, 0, stream>>>(hist, acc);
  k_scan<<<1, NCHUNK, 0, stream>>>(acc);
  k_apply<<<NCHUNK, CHUNK, 0, stream>>>(hist, acc);
  k_fixpass<<<1024, 256, 0, stream>>>(pred, fix, hist, acc);
  k_pass2<<<FRAMES * BPF, 256, 0, stream>>>(pred, gt, acc);
  k_final<<<1, 1, 0, stream>>>(acc, out);
}

// Round 3
// 504.870 us; speedup vs baseline: 1.2894x; 1.2894x over previous
//
#include <hip/hip_runtime.h>
#include <math.h>

constexpr int FRAMES = 32;
constexpr int HW = 720 * 1280;              // 921600
constexpr long long NTOT = (long long)FRAMES * HW;
constexpr int NB = 1 << 20;                 // rank histogram buckets (top-20 encoded bits)
constexpr int CHUNK = 1024;
constexpr int NCHUNK = NB / CHUNK;          // 1024
constexpr int BPF = 60;                     // blocks per frame: 60*256 threads -> 15 float4/thread exact
constexpr int TPB = 256;
constexpr int POS = 15;                     // (HW/4)/(BPF*TPB) = 230400/15360
constexpr int UNR = 5;                      // loads in flight per stream
constexpr size_t HIST_BYTES = (size_t)NB * sizeof(unsigned);

struct Accum {
  double sumP[FRAMES], sumP2[FRAMES], sumFixP[FRAMES], sumG[FRAMES], simSum[FRAMES];
  unsigned cntFix[FRAMES];
  unsigned long long S_cg;      // sum of count_greater over fixation pixels (frame 0)
  unsigned maxCG, Nf0;
  unsigned minP_enc, minG_enc;  // monotone-encoded float mins
  double d_minP, d_scaleP, d_minG, d_scaleG;
  unsigned chunkTotal[NCHUNK];  // becomes exclusive chunk suffix after k_scan
};

// ---------- monotone float<->uint encoding (order-preserving) ----------
__device__ inline unsigned encf(float x) {
  unsigned b = __float_as_uint(x);
  return (b & 0x80000000u) ? ~b : (b | 0x80000000u);
}
__device__ inline float decf(unsigned e) {
  unsigned b = (e & 0x80000000u) ? (e & 0x7FFFFFFFu) : ~e;
  return __uint_as_float(b);
}

// ---------- wave(64) reduction helpers ----------
__device__ inline double wredd(double v) {
  for (int o = 32; o; o >>= 1) v += __shfl_down(v, o, 64);
  return v;
}
__device__ inline unsigned wredu(unsigned v) {
  for (int o = 32; o; o >>= 1) v += __shfl_down(v, o, 64);
  return v;
}
__device__ inline unsigned long long wredull(unsigned long long v) {
  for (int o = 32; o; o >>= 1) v += __shfl_down(v, o, 64);
  return v;
}
__device__ inline unsigned wredumax(unsigned v) {
  for (int o = 32; o; o >>= 1) { unsigned t = __shfl_down(v, o, 64); v = v > t ? v : t; }
  return v;
}
__device__ inline unsigned wredumin(unsigned v) {
  for (int o = 32; o; o >>= 1) { unsigned t = __shfl_down(v, o, 64); v = v < t ? v : t; }
  return v;
}

// ---------- kernels ----------
__global__ void k_init(Accum* acc) {
  acc->minP_enc = 0xFFFFFFFFu;
  acc->minG_enc = 0xFFFFFFFFu;
}

// pred+fix pass: per-frame sumP, sumP2, sumFixP, cntFix; global minP
__global__ __launch_bounds__(TPB) void k_red_pg(const float* __restrict__ pred,
                                                const int* __restrict__ fix,
                                                Accum* __restrict__ acc) {
  const int f = blockIdx.x / BPF, bi = blockIdx.x % BPF;
  const float4* p4 = (const float4*)(pred + (size_t)f * HW);
  const int4* m4 = (const int4*)(fix + (size_t)f * HW);
  const int S = BPF * TPB;
  const int i0 = bi * TPB + threadIdx.x;
  double sP = 0, sP2 = 0, sFP = 0;
  unsigned cnt = 0, mn = 0xFFFFFFFFu;
  for (int r = 0; r < POS / UNR; ++r) {
    float4 p[UNR]; int4 m[UNR];
#pragma unroll
    for (int u = 0; u < UNR; ++u) {
      int i = i0 + (r * UNR + u) * S;
      p[u] = p4[i]; m[u] = m4[i];
    }
#pragma unroll
    for (int u = 0; u < UNR; ++u) {
      float pe[4] = {p[u].x, p[u].y, p[u].z, p[u].w};
      int me[4] = {m[u].x, m[u].y, m[u].z, m[u].w};
#pragma unroll
      for (int j = 0; j < 4; ++j) {
        double pd = (double)pe[j];
        sP += pd; sP2 = fma(pd, pd, sP2);
        if (me[j] != 0) { sFP += pd; cnt++; }
        unsigned e = encf(pe[j]);
        mn = e < mn ? e : mn;
      }
    }
  }
  sP = wredd(sP); sP2 = wredd(sP2); sFP = wredd(sFP);
  cnt = wredu(cnt); mn = wredumin(mn);
  __shared__ double shD[3][TPB / 64];
  __shared__ unsigned shU[2][TPB / 64];
  int w = threadIdx.x >> 6;
  if ((threadIdx.x & 63) == 0) {
    shD[0][w] = sP; shD[1][w] = sP2; shD[2][w] = sFP;
    shU[0][w] = cnt; shU[1][w] = mn;
  }
  __syncthreads();
  if (threadIdx.x == 0) {
    double a = 0, b = 0, c = 0; unsigned d = 0, e = 0xFFFFFFFFu;
#pragma unroll
    for (int k = 0; k < TPB / 64; ++k) {
      a += shD[0][k]; b += shD[1][k]; c += shD[2][k];
      d += shU[0][k]; e = shU[1][k] < e ? shU[1][k] : e;
    }
    atomicAdd(&acc->sumP[f], a);
    atomicAdd(&acc->sumP2[f], b);
    atomicAdd(&acc->sumFixP[f], c);
    atomicAdd(&acc->cntFix[f], d);
    atomicMin(&acc->minP_enc, e);
  }
}

// gt-only pass: per-frame sumG; global minG  (single clean stream)
__global__ __launch_bounds__(TPB) void k_red_g(const float* __restrict__ gt,
                                               Accum* __restrict__ acc) {
  const int f = blockIdx.x / BPF, bi = blockIdx.x % BPF;
  const float4* g4 = (const float4*)(gt + (size_t)f * HW);
  const int S = BPF * TPB;
  const int i0 = bi * TPB + threadIdx.x;
  double sG = 0;
  unsigned mn = 0xFFFFFFFFu;
  for (int r = 0; r < POS / UNR; ++r) {
    float4 g[UNR];
#pragma unroll
    for (int u = 0; u < UNR; ++u) g[u] = g4[i0 + (r * UNR + u) * S];
#pragma unroll
    for (int u = 0; u < UNR; ++u) {
      float ge[4] = {g[u].x, g[u].y, g[u].z, g[u].w};
#pragma unroll
      for (int j = 0; j < 4; ++j) {
        sG += (double)ge[j];
        unsigned e = encf(ge[j]);
        mn = e < mn ? e : mn;
      }
    }
  }
  sG = wredd(sG); mn = wredumin(mn);
  __shared__ double shD[TPB / 64];
  __shared__ unsigned shU[TPB / 64];
  int w = threadIdx.x >> 6;
  if ((threadIdx.x & 63) == 0) { shD[w] = sG; shU[w] = mn; }
  __syncthreads();
  if (threadIdx.x == 0) {
    double a = 0; unsigned e = 0xFFFFFFFFu;
#pragma unroll
    for (int k = 0; k < TPB / 64; ++k) { a += shD[k]; e = shU[k] < e ? shU[k] : e; }
    atomicAdd(&acc->sumG[f], a);
    atomicMin(&acc->minG_enc, e);
  }
}

__global__ void k_derive(Accum* acc) {
  double sp = 0, sg = 0;
  for (int f = 0; f < FRAMES; ++f) { sp += acc->sumP[f]; sg += acc->sumG[f]; }
  acc->d_minP = (double)decf(acc->minP_enc);
  acc->d_minG = (double)decf(acc->minG_enc);
  acc->d_scaleP = 1.0 / (sp - (double)NTOT * acc->d_minP);
  acc->d_scaleG = 1.0 / (sg - (double)NTOT * acc->d_minG);
}

// Histogram of pred[0] keyed by top-20 bits of the monotone encoding.
// Ranks are invariant under minmax normalization, so no min/max needed.
__global__ void k_hist(const float* __restrict__ pred, unsigned* __restrict__ hist) {
  int i = blockIdx.x * TPB + threadIdx.x;   // grid covers HW/4 exactly (900*256)
  float4 p = ((const float4*)pred)[i];
  atomicAdd(&hist[encf(p.x) >> 12], 1u);
  atomicAdd(&hist[encf(p.y) >> 12], 1u);
  atomicAdd(&hist[encf(p.z) >> 12], 1u);
  atomicAdd(&hist[encf(p.w) >> 12], 1u);
}

// Per-chunk totals
__global__ void k_chunktot(const unsigned* __restrict__ hist, Accum* __restrict__ acc) {
  __shared__ unsigned sw[4];
  const int c = blockIdx.x;
  unsigned s = 0;
  for (int t = threadIdx.x; t < CHUNK; t += blockDim.x) s += hist[(size_t)c * CHUNK + t];
  s = wredu(s);
  if ((threadIdx.x & 63) == 0) sw[threadIdx.x >> 6] = s;
  __syncthreads();
  if (threadIdx.x == 0) acc->chunkTotal[c] = sw[0] + sw[1] + sw[2] + sw[3];
}

// Single-block exclusive suffix scan over NCHUNK chunk totals (in place)
__global__ void k_scan(Accum* acc) {
  __shared__ unsigned s[NCHUNK];
  const int t = threadIdx.x;
  unsigned v = acc->chunkTotal[t];
  s[t] = v;
  __syncthreads();
  for (int off = 1; off < NCHUNK; off <<= 1) {
    unsigned a = (t + off < NCHUNK) ? s[t + off] : 0u;
    __syncthreads();
    s[t] += a;
    __syncthreads();
  }
  acc->chunkTotal[t] = s[t] - v;  // strictly-greater-chunk sum
}

// In place: hist[b] := #elements in buckets strictly greater than b
__global__ void k_apply(unsigned* __restrict__ hist, const Accum* __restrict__ acc) {
  __shared__ unsigned s[CHUNK];
  const int c = blockIdx.x, t = threadIdx.x;
  unsigned v = hist[(size_t)c * CHUNK + t];
  s[t] = v;
  __syncthreads();
  for (int off = 1; off < CHUNK; off <<= 1) {
    unsigned a = (t + off < CHUNK) ? s[t + off] : 0u;
    __syncthreads();
    s[t] += a;
    __syncthreads();
  }
  hist[(size_t)c * CHUNK + t] = acc->chunkTotal[c] + (s[t] - v);
}

// Accumulate sum / max of count_greater over fixation pixels of frame 0
__global__ void k_fixpass(const float* __restrict__ pred, const int* __restrict__ fix,
                          const unsigned* __restrict__ hist, Accum* __restrict__ acc) {
  int i = blockIdx.x * TPB + threadIdx.x;   // grid covers HW/4 exactly
  float4 p = ((const float4*)pred)[i];
  int4 m = ((const int4*)fix)[i];
  float pe[4] = {p.x, p.y, p.z, p.w};
  int me[4] = {m.x, m.y, m.z, m.w};
  unsigned long long s = 0;
  unsigned mx = 0, c = 0;
#pragma unroll
  for (int j = 0; j < 4; ++j) {
    if (me[j] > 0) {
      unsigned cg = hist[encf(pe[j]) >> 12];
      s += cg;
      mx = cg > mx ? cg : mx;
      c++;
    }
  }
  s = wredull(s); mx = wredumax(mx); c = wredu(c);
  __shared__ unsigned long long shS[4];
  __shared__ unsigned shM[4], shC[4];
  int w = threadIdx.x >> 6;
  if ((threadIdx.x & 63) == 0) { shS[w] = s; shM[w] = mx; shC[w] = c; }
  __syncthreads();
  if (threadIdx.x == 0) {
    unsigned long long ts = 0; unsigned tm = 0, tc = 0;
#pragma unroll
    for (int k = 0; k < 4; ++k) {
      ts += shS[k]; tm = shM[k] > tm ? shM[k] : tm; tc += shC[k];
    }
    atomicAdd(&acc->S_cg, ts);
    atomicMax(&acc->maxCG, tm);
    atomicAdd(&acc->Nf0, tc);
  }
}

// SIM pass: per-frame sum of min(p_norm, g_norm) where g_raw > minG
__global__ __launch_bounds__(TPB) void k_pass2(const float* __restrict__ pred,
                                               const float* __restrict__ gt,
                                               Accum* __restrict__ acc) {
  const int f = blockIdx.x / BPF, bi = blockIdx.x % BPF;
  const float4* p4 = (const float4*)(pred + (size_t)f * HW);
  const float4* g4 = (const float4*)(gt + (size_t)f * HW);
  const int S = BPF * TPB;
  const int i0 = bi * TPB + threadIdx.x;
  const double minP = acc->d_minP, sclP = acc->d_scaleP;
  const double minG = acc->d_minG, sclG = acc->d_scaleG;
  const float fminG = (float)minG;
  double s = 0;
  for (int r = 0; r < POS / UNR; ++r) {
    float4 p[UNR], g[UNR];
#pragma unroll
    for (int u = 0; u < UNR; ++u) {
      int i = i0 + (r * UNR + u) * S;
      p[u] = p4[i]; g[u] = g4[i];
    }
#pragma unroll
    for (int u = 0; u < UNR; ++u) {
      float pe[4] = {p[u].x, p[u].y, p[u].z, p[u].w};
      float ge[4] = {g[u].x, g[u].y, g[u].z, g[u].w};
#pragma unroll
      for (int j = 0; j < 4; ++j) {
        if (ge[j] > fminG) {
          double pn = ((double)pe[j] - minP) * sclP;
          double gn = ((double)ge[j] - minG) * sclG;
          s += pn < gn ? pn : gn;
        }
      }
    }
  }
  s = wredd(s);
  __shared__ double shD[TPB / 64];
  int w = threadIdx.x >> 6;
  if ((threadIdx.x & 63) == 0) shD[w] = s;
  __syncthreads();
  if (threadIdx.x == 0) {
    double a = 0;
#pragma unroll
    for (int k = 0; k < TPB / 64; ++k) a += shD[k];
    atomicAdd(&acc->simSum[f], a);
  }
}

__global__ void k_final(const Accum* __restrict__ acc, float* __restrict__ out) {
  if (threadIdx.x != 0 || blockIdx.x != 0) return;
  double sim = 0, nss = 0;
  for (int f = 0; f < FRAMES; ++f) sim += acc->simSum[f];
  sim /= FRAMES;
  for (int f = 0; f < FRAMES; ++f) {
    double mean = acc->sumP[f] / (double)HW;
    double var = acc->sumP2[f] / (double)HW - mean * mean;
    double sd = sqrt(var);
    double cnt = (double)acc->cntFix[f];
    nss += (acc->sumFixP[f] - cnt * mean) / sd / cnt;
  }
  nss /= FRAMES;
  // AUC-Judd closed form: AUC = [2NfD + (Nf-1)^2 + R_last - 2*SumR] / (2NfD)
  double Nf = (double)acc->Nf0;
  double D = (double)HW - Nf;
  double SumR = (double)acc->S_cg + Nf;         // ranks are count_greater + 1
  double Rlast = (double)acc->maxCG + 1.0;
  double auc = (2.0 * Nf * D + (Nf - 1.0) * (Nf - 1.0) + Rlast - 2.0 * SumR) / (2.0 * Nf * D);
  out[0] = (float)(auc + sim + nss);
  out[1] = (float)auc;
  out[2] = (float)sim;
  out[3] = (float)nss;
}

extern "C" void kernel_launch(void* const* d_in, const int* in_sizes, int n_in,
                              void* d_out, int out_size, void* d_ws, size_t ws_size,
                              hipStream_t stream) {
  const float* pred = (const float*)d_in[0];
  const float* gt = (const float*)d_in[1];
  const int* fix = (const int*)d_in[2];
  float* out = (float*)d_out;
  unsigned* hist = (unsigned*)d_ws;
  Accum* acc = (Accum*)((char*)d_ws + HIST_BYTES);

  hipMemsetAsync(d_ws, 0, HIST_BYTES + sizeof(Accum), stream);
  k_init<<<1, 1, 0, stream>>>(acc);
  k_hist<<<HW / 4 / TPB, TPB, 0, stream>>>(pred, hist);          // 900 blocks
  k_red_pg<<<FRAMES * BPF, TPB, 0, stream>>>(pred, fix, acc);    // 1920 blocks
  k_red_g<<<FRAMES * BPF, TPB, 0, stream>>>(gt, acc);
  k_derive<<<1, 1, 0, stream>>>(acc);
  k_chunktot<<<NCHUNK, 256, 0, stream>>>(hist, acc);
  k_scan<<<1, NCHUNK, 0, stream>>>(acc);
  k_apply<<<NCHUNK, CHUNK, 0, stream>>>(hist, acc);
  k_fixpass<<<HW / 4 / TPB, TPB, 0, stream>>>(pred, fix, hist, acc);
  k_pass2<<<FRAMES * BPF, TPB, 0, stream>>>(pred, gt, acc);
  k_final<<<1, 1, 0, stream>>>(acc, out);
}

// Round 4
// 500.790 us; speedup vs baseline: 1.2999x; 1.0081x over previous
//
#include <hip/hip_runtime.h>
#include <math.h>

constexpr int FRAMES = 32;
constexpr int HW = 720 * 1280;              // 921600
constexpr long long NTOT = (long long)FRAMES * HW;
constexpr int NB = 1 << 20;                 // rank histogram buckets (top-20 encoded bits)
constexpr int CHUNK = 1024;
constexpr int NCHUNK = NB / CHUNK;          // 1024
constexpr int BPF = 60;                     // blocks per frame: 60*256 threads -> 15 float4/thread exact
constexpr int TPB = 256;
constexpr int POS = 15;                     // (HW/4)/(BPF*TPB) = 230400/15360
constexpr int UNR = 5;                      // loads in flight per stream
constexpr size_t HIST_BYTES = (size_t)NB * sizeof(unsigned);

struct Accum {
  double sumP[FRAMES], sumP2[FRAMES], sumFixP[FRAMES], sumG[FRAMES], simSum[FRAMES];
  unsigned cntFix[FRAMES];
  unsigned long long S_cg;      // sum of count_greater over fixation pixels (frame 0)
  unsigned maxCG, Nf0;
  unsigned minP_enc, minG_enc;  // monotone-encoded float mins
  double d_minP, d_scaleP, d_minG, d_scaleG;
  unsigned chunkTotal[NCHUNK];  // becomes exclusive chunk suffix after k_scan
};

// ---------- monotone float<->uint encoding (order-preserving) ----------
__device__ inline unsigned encf(float x) {
  unsigned b = __float_as_uint(x);
  return (b & 0x80000000u) ? ~b : (b | 0x80000000u);
}
__device__ inline float decf(unsigned e) {
  unsigned b = (e & 0x80000000u) ? (e & 0x7FFFFFFFu) : ~e;
  return __uint_as_float(b);
}

// ---------- wave(64) reduction helpers ----------
__device__ inline double wredd(double v) {
  for (int o = 32; o; o >>= 1) v += __shfl_down(v, o, 64);
  return v;
}
__device__ inline unsigned wredu(unsigned v) {
  for (int o = 32; o; o >>= 1) v += __shfl_down(v, o, 64);
  return v;
}
__device__ inline unsigned long long wredull(unsigned long long v) {
  for (int o = 32; o; o >>= 1) v += __shfl_down(v, o, 64);
  return v;
}
__device__ inline unsigned wredumax(unsigned v) {
  for (int o = 32; o; o >>= 1) { unsigned t = __shfl_down(v, o, 64); v = v > t ? v : t; }
  return v;
}
__device__ inline unsigned wredumin(unsigned v) {
  for (int o = 32; o; o >>= 1) { unsigned t = __shfl_down(v, o, 64); v = v < t ? v : t; }
  return v;
}

// ---------- kernels ----------
__global__ void k_init(Accum* acc) {
  acc->minP_enc = 0xFFFFFFFFu;
  acc->minG_enc = 0xFFFFFFFFu;
}

// pred+fix pass: per-frame sumP, sumP2, sumFixP, cntFix; global minP
__global__ __launch_bounds__(TPB) void k_red_pg(const float* __restrict__ pred,
                                                const int* __restrict__ fix,
                                                Accum* __restrict__ acc) {
  const int f = blockIdx.x / BPF, bi = blockIdx.x % BPF;
  const float4* p4 = (const float4*)(pred + (size_t)f * HW);
  const int4* m4 = (const int4*)(fix + (size_t)f * HW);
  const int S = BPF * TPB;
  const int i0 = bi * TPB + threadIdx.x;
  double sP = 0, sP2 = 0, sFP = 0;
  unsigned cnt = 0, mn = 0xFFFFFFFFu;
  for (int r = 0; r < POS / UNR; ++r) {
    float4 p[UNR]; int4 m[UNR];
#pragma unroll
    for (int u = 0; u < UNR; ++u) {
      int i = i0 + (r * UNR + u) * S;
      p[u] = p4[i]; m[u] = m4[i];
    }
    // Pin the batch: loads above may not sink below this point, so all UNR
    // float4/int4 buffers must materialize in VGPRs (verify: VGPR_Count >= 56).
    __builtin_amdgcn_sched_barrier(0);
#pragma unroll
    for (int u = 0; u < UNR; ++u) {
      float pe[4] = {p[u].x, p[u].y, p[u].z, p[u].w};
      int me[4] = {m[u].x, m[u].y, m[u].z, m[u].w};
#pragma unroll
      for (int j = 0; j < 4; ++j) {
        double pd = (double)pe[j];
        sP += pd; sP2 = fma(pd, pd, sP2);
        if (me[j] != 0) { sFP += pd; cnt++; }
        unsigned e = encf(pe[j]);
        mn = e < mn ? e : mn;
      }
    }
  }
  sP = wredd(sP); sP2 = wredd(sP2); sFP = wredd(sFP);
  cnt = wredu(cnt); mn = wredumin(mn);
  __shared__ double shD[3][TPB / 64];
  __shared__ unsigned shU[2][TPB / 64];
  int w = threadIdx.x >> 6;
  if ((threadIdx.x & 63) == 0) {
    shD[0][w] = sP; shD[1][w] = sP2; shD[2][w] = sFP;
    shU[0][w] = cnt; shU[1][w] = mn;
  }
  __syncthreads();
  if (threadIdx.x == 0) {
    double a = 0, b = 0, c = 0; unsigned d = 0, e = 0xFFFFFFFFu;
#pragma unroll
    for (int k = 0; k < TPB / 64; ++k) {
      a += shD[0][k]; b += shD[1][k]; c += shD[2][k];
      d += shU[0][k]; e = shU[1][k] < e ? shU[1][k] : e;
    }
    atomicAdd(&acc->sumP[f], a);
    atomicAdd(&acc->sumP2[f], b);
    atomicAdd(&acc->sumFixP[f], c);
    atomicAdd(&acc->cntFix[f], d);
    atomicMin(&acc->minP_enc, e);
  }
}

// gt-only pass: per-frame sumG; global minG  (single clean stream)
__global__ __launch_bounds__(TPB) void k_red_g(const float* __restrict__ gt,
                                               Accum* __restrict__ acc) {
  const int f = blockIdx.x / BPF, bi = blockIdx.x % BPF;
  const float4* g4 = (const float4*)(gt + (size_t)f * HW);
  const int S = BPF * TPB;
  const int i0 = bi * TPB + threadIdx.x;
  double sG = 0;
  unsigned mn = 0xFFFFFFFFu;
  for (int r = 0; r < POS / UNR; ++r) {
    float4 g[UNR];
#pragma unroll
    for (int u = 0; u < UNR; ++u) g[u] = g4[i0 + (r * UNR + u) * S];
    __builtin_amdgcn_sched_barrier(0);
#pragma unroll
    for (int u = 0; u < UNR; ++u) {
      float ge[4] = {g[u].x, g[u].y, g[u].z, g[u].w};
#pragma unroll
      for (int j = 0; j < 4; ++j) {
        sG += (double)ge[j];
        unsigned e = encf(ge[j]);
        mn = e < mn ? e : mn;
      }
    }
  }
  sG = wredd(sG); mn = wredumin(mn);
  __shared__ double shD[TPB / 64];
  __shared__ unsigned shU[TPB / 64];
  int w = threadIdx.x >> 6;
  if ((threadIdx.x & 63) == 0) { shD[w] = sG; shU[w] = mn; }
  __syncthreads();
  if (threadIdx.x == 0) {
    double a = 0; unsigned e = 0xFFFFFFFFu;
#pragma unroll
    for (int k = 0; k < TPB / 64; ++k) { a += shD[k]; e = shU[k] < e ? shU[k] : e; }
    atomicAdd(&acc->sumG[f], a);
    atomicMin(&acc->minG_enc, e);
  }
}

__global__ void k_derive(Accum* acc) {
  double sp = 0, sg = 0;
  for (int f = 0; f < FRAMES; ++f) { sp += acc->sumP[f]; sg += acc->sumG[f]; }
  acc->d_minP = (double)decf(acc->minP_enc);
  acc->d_minG = (double)decf(acc->minG_enc);
  acc->d_scaleP = 1.0 / (sp - (double)NTOT * acc->d_minP);
  acc->d_scaleG = 1.0 / (sg - (double)NTOT * acc->d_minG);
}

// Histogram of pred[0] keyed by top-20 bits of the monotone encoding.
// Ranks are invariant under minmax normalization, so no min/max needed.
__global__ void k_hist(const float* __restrict__ pred, unsigned* __restrict__ hist) {
  int i = blockIdx.x * TPB + threadIdx.x;   // grid covers HW/4 exactly (900*256)
  float4 p = ((const float4*)pred)[i];
  atomicAdd(&hist[encf(p.x) >> 12], 1u);
  atomicAdd(&hist[encf(p.y) >> 12], 1u);
  atomicAdd(&hist[encf(p.z) >> 12], 1u);
  atomicAdd(&hist[encf(p.w) >> 12], 1u);
}

// Per-chunk totals
__global__ void k_chunktot(const unsigned* __restrict__ hist, Accum* __restrict__ acc) {
  __shared__ unsigned sw[4];
  const int c = blockIdx.x;
  unsigned s = 0;
  for (int t = threadIdx.x; t < CHUNK; t += blockDim.x) s += hist[(size_t)c * CHUNK + t];
  s = wredu(s);
  if ((threadIdx.x & 63) == 0) sw[threadIdx.x >> 6] = s;
  __syncthreads();
  if (threadIdx.x == 0) acc->chunkTotal[c] = sw[0] + sw[1] + sw[2] + sw[3];
}

// Single-block exclusive suffix scan over NCHUNK chunk totals (in place)
__global__ void k_scan(Accum* acc) {
  __shared__ unsigned s[NCHUNK];
  const int t = threadIdx.x;
  unsigned v = acc->chunkTotal[t];
  s[t] = v;
  __syncthreads();
  for (int off = 1; off < NCHUNK; off <<= 1) {
    unsigned a = (t + off < NCHUNK) ? s[t + off] : 0u;
    __syncthreads();
    s[t] += a;
    __syncthreads();
  }
  acc->chunkTotal[t] = s[t] - v;  // strictly-greater-chunk sum
}

// In place: hist[b] := #elements in buckets strictly greater than b
__global__ void k_apply(unsigned* __restrict__ hist, const Accum* __restrict__ acc) {
  __shared__ unsigned s[CHUNK];
  const int c = blockIdx.x, t = threadIdx.x;
  unsigned v = hist[(size_t)c * CHUNK + t];
  s[t] = v;
  __syncthreads();
  for (int off = 1; off < CHUNK; off <<= 1) {
    unsigned a = (t + off < CHUNK) ? s[t + off] : 0u;
    __syncthreads();
    s[t] += a;
    __syncthreads();
  }
  hist[(size_t)c * CHUNK + t] = acc->chunkTotal[c] + (s[t] - v);
}

// Accumulate sum / max of count_greater over fixation pixels of frame 0
__global__ void k_fixpass(const float* __restrict__ pred, const int* __restrict__ fix,
                          const unsigned* __restrict__ hist, Accum* __restrict__ acc) {
  int i = blockIdx.x * TPB + threadIdx.x;   // grid covers HW/4 exactly
  float4 p = ((const float4*)pred)[i];
  int4 m = ((const int4*)fix)[i];
  float pe[4] = {p.x, p.y, p.z, p.w};
  int me[4] = {m.x, m.y, m.z, m.w};
  unsigned long long s = 0;
  unsigned mx = 0, c = 0;
#pragma unroll
  for (int j = 0; j < 4; ++j) {
    if (me[j] > 0) {
      unsigned cg = hist[encf(pe[j]) >> 12];
      s += cg;
      mx = cg > mx ? cg : mx;
      c++;
    }
  }
  s = wredull(s); mx = wredumax(mx); c = wredu(c);
  __shared__ unsigned long long shS[4];
  __shared__ unsigned shM[4], shC[4];
  int w = threadIdx.x >> 6;
  if ((threadIdx.x & 63) == 0) { shS[w] = s; shM[w] = mx; shC[w] = c; }
  __syncthreads();
  if (threadIdx.x == 0) {
    unsigned long long ts = 0; unsigned tm = 0, tc = 0;
#pragma unroll
    for (int k = 0; k < 4; ++k) {
      ts += shS[k]; tm = shM[k] > tm ? shM[k] : tm; tc += shC[k];
    }
    atomicAdd(&acc->S_cg, ts);
    atomicMax(&acc->maxCG, tm);
    atomicAdd(&acc->Nf0, tc);
  }
}

// SIM pass: per-frame sum of min(p_norm, g_norm) where g_raw > minG
__global__ __launch_bounds__(TPB) void k_pass2(const float* __restrict__ pred,
                                               const float* __restrict__ gt,
                                               Accum* __restrict__ acc) {
  const int f = blockIdx.x / BPF, bi = blockIdx.x % BPF;
  const float4* p4 = (const float4*)(pred + (size_t)f * HW);
  const float4* g4 = (const float4*)(gt + (size_t)f * HW);
  const int S = BPF * TPB;
  const int i0 = bi * TPB + threadIdx.x;
  const double minP = acc->d_minP, sclP = acc->d_scaleP;
  const double minG = acc->d_minG, sclG = acc->d_scaleG;
  const float fminG = (float)minG;
  double s = 0;
  for (int r = 0; r < POS / UNR; ++r) {
    float4 p[UNR], g[UNR];
#pragma unroll
    for (int u = 0; u < UNR; ++u) {
      int i = i0 + (r * UNR + u) * S;
      p[u] = p4[i]; g[u] = g4[i];
    }
    __builtin_amdgcn_sched_barrier(0);
#pragma unroll
    for (int u = 0; u < UNR; ++u) {
      float pe[4] = {p[u].x, p[u].y, p[u].z, p[u].w};
      float ge[4] = {g[u].x, g[u].y, g[u].z, g[u].w};
#pragma unroll
      for (int j = 0; j < 4; ++j) {
        if (ge[j] > fminG) {
          double pn = ((double)pe[j] - minP) * sclP;
          double gn = ((double)ge[j] - minG) * sclG;
          s += pn < gn ? pn : gn;
        }
      }
    }
  }
  s = wredd(s);
  __shared__ double shD[TPB / 64];
  int w = threadIdx.x >> 6;
  if ((threadIdx.x & 63) == 0) shD[w] = s;
  __syncthreads();
  if (threadIdx.x == 0) {
    double a = 0;
#pragma unroll
    for (int k = 0; k < TPB / 64; ++k) a += shD[k];
    atomicAdd(&acc->simSum[f], a);
  }
}

__global__ void k_final(const Accum* __restrict__ acc, float* __restrict__ out) {
  if (threadIdx.x != 0 || blockIdx.x != 0) return;
  double sim = 0, nss = 0;
  for (int f = 0; f < FRAMES; ++f) sim += acc->simSum[f];
  sim /= FRAMES;
  for (int f = 0; f < FRAMES; ++f) {
    double mean = acc->sumP[f] / (double)HW;
    double var = acc->sumP2[f] / (double)HW - mean * mean;
    double sd = sqrt(var);
    double cnt = (double)acc->cntFix[f];
    nss += (acc->sumFixP[f] - cnt * mean) / sd / cnt;
  }
  nss /= FRAMES;
  // AUC-Judd closed form: AUC = [2NfD + (Nf-1)^2 + R_last - 2*SumR] / (2NfD)
  double Nf = (double)acc->Nf0;
  double D = (double)HW - Nf;
  double SumR = (double)acc->S_cg + Nf;         // ranks are count_greater + 1
  double Rlast = (double)acc->maxCG + 1.0;
  double auc = (2.0 * Nf * D + (Nf - 1.0) * (Nf - 1.0) + Rlast - 2.0 * SumR) / (2.0 * Nf * D);
  out[0] = (float)(auc + sim + nss);
  out[1] = (float)auc;
  out[2] = (float)sim;
  out[3] = (float)nss;
}

extern "C" void kernel_launch(void* const* d_in, const int* in_sizes, int n_in,
                              void* d_out, int out_size, void* d_ws, size_t ws_size,
                              hipStream_t stream) {
  const float* pred = (const float*)d_in[0];
  const float* gt = (const float*)d_in[1];
  const int* fix = (const int*)d_in[2];
  float* out = (float*)d_out;
  unsigned* hist = (unsigned*)d_ws;
  Accum* acc = (Accum*)((char*)d_ws + HIST_BYTES);

  hipMemsetAsync(d_ws, 0, HIST_BYTES + sizeof(Accum), stream);
  k_init<<<1, 1, 0, stream>>>(acc);
  k_hist<<<HW / 4 / TPB, TPB, 0, stream>>>(pred, hist);          // 900 blocks
  k_red_pg<<<FRAMES * BPF, TPB, 0, stream>>>(pred, fix, acc);    // 1920 blocks
  k_red_g<<<FRAMES * BPF, TPB, 0, stream>>>(gt, acc);
  k_derive<<<1, 1, 0, stream>>>(acc);
  k_chunktot<<<NCHUNK, 256, 0, stream>>>(hist, acc);
  k_scan<<<1, NCHUNK, 0, stream>>>(acc);
  k_apply<<<NCHUNK, CHUNK, 0, stream>>>(hist, acc);
  k_fixpass<<<HW / 4 / TPB, TPB, 0, stream>>>(pred, fix, hist, acc);
  k_pass2<<<FRAMES * BPF, TPB, 0, stream>>>(pred, gt, acc);
  k_final<<<1, 1, 0, stream>>>(acc, out);
}